// Round 1
// baseline (181.468 us; speedup 1.0000x reference)
//
#include <hip/hip_runtime.h>

// Corr2Cost: out[b,c,k,h,w] = bilinear-gather of corr[b,c,:,h,w] along D at
// pos = (is_ux ? w : h) + (k - maxdisp), zero-padded outside [0, D-1].
// Shapes fixed by the harness: corr (8,2,128,96,128) f32, maxdisp=50 -> K=101.
//
// Strategy: one block per (b,c,h). Stage the D x W = 128x128 f32 slice
// (64 KB) into LDS with coalesced 512B row loads (rows are 48KB apart in
// global), then emit the K x W output tile with coalesced stores. The
// diagonal LDS gather has per-lane stride 129 floats (odd) -> conflict-free.

#define B_ 8
#define C_ 2
#define D_ 128
#define H_ 96
#define W_ 128
#define NTHREADS 256

__global__ __launch_bounds__(NTHREADS) void corr2cost_kernel(
    const float* __restrict__ corr,
    const int* __restrict__ maxdisp_p,
    const int* __restrict__ isux_p,
    float* __restrict__ out) {
  __shared__ float lds[D_ * W_];  // 64 KB: lds[d*W_ + w]

  const int t   = threadIdx.x;
  const int bid = blockIdx.x;        // = (b*C + c)*H + h
  const int h   = bid % H_;
  const int bc  = bid / H_;
  const int HW  = H_ * W_;

  // ---- stage corr[b,c,:,h,:] into LDS (coalesced float4 row loads) ----
  const float* __restrict__ src = corr + (size_t)bc * D_ * HW + (size_t)h * W_;
  const int n4 = D_ * W_ / 4;  // 4096 float4, 16 per thread
#pragma unroll
  for (int i = t; i < n4; i += NTHREADS) {
    const int d  = i >> 5;       // 32 float4 per 128-float row
    const int w4 = i & 31;
    const float4 v = *reinterpret_cast<const float4*>(src + (size_t)d * HW + w4 * 4);
    *reinterpret_cast<float4*>(&lds[d * W_ + w4 * 4]) = v;
  }
  __syncthreads();

  // ---- compute K x W outputs, coalesced over w ----
  const int maxdisp = *maxdisp_p;
  const int is_ux   = *isux_p;
  const int K       = 2 * maxdisp + 1;

  const int w    = t & (W_ - 1);   // lane's column
  const int k0   = t >> 7;         // 0 or 1 (two k-phases per block)
  const int base = is_ux ? w : h;

  float* __restrict__ dst = out + (size_t)bc * K * HW + (size_t)h * W_ + w;

  for (int k = k0; k < K; k += 2) {
    // Reference math: pos = base + dx, dx = -maxdisp + k (linspace step == 1.0)
    const float posf = (float)(base + k - maxdisp);
    const float i0f  = floorf(posf);
    const float w1   = posf - i0f;           // == 0 for integer dx, kept for exact semantics
    const int   i0   = (int)i0f;
    const int   i1   = i0 + 1;
    const float g0 = (i0 >= 0 && i0 < D_) ? lds[i0 * W_ + w] : 0.0f;
    const float g1 = (i1 >= 0 && i1 < D_) ? lds[i1 * W_ + w] : 0.0f;
    dst[(size_t)k * HW] = g0 * (1.0f - w1) + g1 * w1;
  }
}

extern "C" void kernel_launch(void* const* d_in, const int* in_sizes, int n_in,
                              void* d_out, int out_size, void* d_ws, size_t ws_size,
                              hipStream_t stream) {
  const float* corr    = (const float*)d_in[0];
  const int*   maxdisp = (const int*)d_in[1];
  const int*   is_ux   = (const int*)d_in[2];
  float*       out     = (float*)d_out;

  const int grid = B_ * C_ * H_;  // 1536 blocks, one per (b,c,h)
  corr2cost_kernel<<<grid, NTHREADS, 0, stream>>>(corr, maxdisp, is_ux, out);
}

// Round 2
// 174.660 us; speedup vs baseline: 1.0390x; 1.0390x over previous
//
#include <hip/hip_runtime.h>

// Corr2Cost: out[b,c,k,h,w] = bilinear-gather of corr[b,c,:,h,w] along D at
// pos = (is_ux ? w : h) + (k - maxdisp), zero-padded outside [0, D-1].
// Harness shapes: corr (8,2,128,96,128) f32, maxdisp=50 -> K=101, is_ux=1.
//
// R2 strategy: one block per (b,c,h, 32-wide w-tile). Only the d-rows the
// tile can touch ([w0-m, w0+WT+m] clipped, <=128) are staged -> 16 KB LDS,
// 8 blocks/CU, 32 waves/CU (vs R1's 64 KB -> 2 blocks/CU, 19% occupancy).
// Also cuts input reads to ~77% (diamond support). LDS gather address is
// 33*wi + c -> conflict-free (R1 measured 0 conflicts with same idiom).

#define B_ 8
#define C_ 2
#define D_ 128
#define H_ 96
#define W_ 128
#define WT 32           // w-tile width
#define NT 256

__global__ __launch_bounds__(NT, 8) void corr2cost_kernel(
    const float* __restrict__ corr,
    const int* __restrict__ maxdisp_p,
    const int* __restrict__ isux_p,
    float* __restrict__ out) {
  __shared__ float lds[D_ * WT];  // 16 KB, rows indexed relative to dlo

  const int t   = threadIdx.x;
  const int bid = blockIdx.x;
  const int wt   = bid & (W_ / WT - 1);
  const int rest = bid >> 2;           // W_/WT == 4
  const int h    = rest % H_;
  const int bc   = rest / H_;
  const int w0   = wt * WT;
  const int HW   = H_ * W_;

  const int m     = *maxdisp_p;
  const int is_ux = *isux_p;
  const int K     = 2 * m + 1;

  // d-rows this tile's taps can touch: i0 in [base-m, base+m], i1 = i0+1.
  int dlo = (is_ux ? w0 : h) - m;
  int dhi = (is_ux ? w0 + WT - 1 : h) + m + 1;  // +1 covers the g1 tap
  dlo = dlo > 0 ? dlo : 0;
  dhi = dhi < D_ - 1 ? dhi : D_ - 1;

  // ---- stage rows [dlo, dhi] of corr[b,c,:,h,w0:w0+WT] ----
  const float* __restrict__ src =
      corr + (size_t)bc * D_ * HW + (size_t)h * W_ + w0;
  const int r0 = t >> 3;              // 32 rows per pass (8 float4 per row)
  const int c4 = (t & 7) * 4;
  for (int r = dlo + r0; r <= dhi; r += 32) {
    *reinterpret_cast<float4*>(&lds[(r - dlo) * WT + c4]) =
        *reinterpret_cast<const float4*>(src + (size_t)r * HW + c4);
  }
  __syncthreads();

  // ---- emit K x WT outputs, coalesced over w ----
  const int wi   = t & (WT - 1);
  const int kg   = t >> 5;            // 8 k-groups
  const int base = is_ux ? (w0 + wi) : h;

  float* __restrict__ dst =
      out + (size_t)bc * K * HW + (size_t)h * W_ + w0 + wi;

  for (int k = kg; k < K; k += NT / WT) {
    const float posf = (float)(base + k - m);   // linspace step is exactly 1.0
    const float i0f  = floorf(posf);
    const float w1   = posf - i0f;
    const int   i0   = (int)i0f;
    const int   i1   = i0 + 1;
    const float g0 = (i0 >= 0 && i0 < D_) ? lds[(i0 - dlo) * WT + wi] : 0.0f;
    const float g1 = (i1 >= 0 && i1 < D_) ? lds[(i1 - dlo) * WT + wi] : 0.0f;
    dst[(size_t)k * HW] = g0 * (1.0f - w1) + g1 * w1;
  }
}

extern "C" void kernel_launch(void* const* d_in, const int* in_sizes, int n_in,
                              void* d_out, int out_size, void* d_ws, size_t ws_size,
                              hipStream_t stream) {
  const float* corr    = (const float*)d_in[0];
  const int*   maxdisp = (const int*)d_in[1];
  const int*   is_ux   = (const int*)d_in[2];
  float*       out     = (float*)d_out;

  const int grid = B_ * C_ * H_ * (W_ / WT);  // 6144 blocks
  corr2cost_kernel<<<grid, NT, 0, stream>>>(corr, maxdisp, is_ux, out);
}